// Round 10
// baseline (208.296 us; speedup 1.0000x reference)
//
#include <hip/hip_runtime.h>

#define S 2048
#define H 1024
#define NH 16
#define HD 64
#define WIN 512
// Q pre-scale: (1/sqrt(64)) * log2(e)  -> scores arrive in log2 domain
#define SCALE_Q 0.18033688f
#define SM_SHIFT 16.0f

typedef unsigned short u16;
typedef unsigned int u32;
typedef __attribute__((ext_vector_type(8))) short bfrag;   // 8 bf16 (4 VGPRs)
typedef __attribute__((ext_vector_type(4))) float facc;    // 4 f32 acc
typedef __attribute__((ext_vector_type(4))) unsigned short u16x4;

#define VMCNT(n) asm volatile("s_waitcnt vmcnt(" #n ")" ::: "memory")

// ---- workspace layout (u16 elements), total 30.25M el = 60.5 MB ------------
constexpr size_t M1    = 1u << 20;
constexpr size_t WTO   = 0;                      // 8M  transposed weights / split partials
constexpr size_t XBO   = 8 * M1;                 // 2M  x bf16; later VT0
constexpr size_t MEMBO = 10 * M1;                // 0.5M
constexpr size_t PERBO = MEMBO + (M1 >> 1);      // 64K
constexpr size_t QO    = PERBO + (M1 >> 4);      // 8M  Q0..Q3 (2M each)
constexpr size_t KVO   = QO + 8 * M1;            // 8M  K0,V0,K1,V1; later out4
constexpr size_t K2O   = KVO + 8 * M1;           // 0.5M
constexpr size_t V2O   = K2O + (M1 >> 1);        // 0.5M
constexpr size_t K3O   = V2O + (M1 >> 1);        // 64K
constexpr size_t V3O   = K3O + (M1 >> 4);        // 64K
constexpr size_t VT1O  = V3O + (M1 >> 4);        // 2M
constexpr size_t VT2O  = VT1O + 2 * M1;          // 0.5M
constexpr size_t VT3O  = VT2O + (M1 >> 1);       // 64K
// split-KV partial records (f32, overlay WTO region between phases B and D):
// 256 records x 8704 f32 (8192 O^T + 512 l) = 8.9 MB
constexpr size_t RECSZ = 8704;

__device__ __forceinline__ u16 f2bf(float f) {
    union { float f; unsigned u; } v; v.f = f;
    unsigned r = v.u + 0x7fffu + ((v.u >> 16) & 1u);   // RNE
    return (u16)(r >> 16);
}
__device__ __forceinline__ float bf2f(u16 b) {
    union { unsigned u; float f; } v; v.u = ((unsigned)b) << 16;
    return v.f;
}
// async global->LDS, 16B per lane; LDS dest = wave-uniform base + lane*16
__device__ __forceinline__ void gload16(const u16* g, u16* l) {
    __builtin_amdgcn_global_load_lds(
        (const __attribute__((address_space(1))) u32*)g,
        (__attribute__((address_space(3))) u32*)l, 16, 0, 0);
}
// pack two f32 -> 2xbf16 in one u32 (low = a, high = b), RNE
__device__ __forceinline__ u32 cvt_pk(float a, float b) {
    u32 w;
    asm("v_cvt_pk_bf16_f32 %0, %1, %2" : "=v"(w) : "v"(a), "v"(b));
    return w;
}
// raw workgroup barrier with compiler memory fence (NO vmcnt drain)
__device__ __forceinline__ void blockbar() {
    __builtin_amdgcn_sched_barrier(0);
    asm volatile("" ::: "memory");
    __builtin_amdgcn_s_barrier();
    asm volatile("" ::: "memory");
    __builtin_amdgcn_sched_barrier(0);
}

// ---------------------------------------------------------------------------
// fp32 -> bf16 cast of x, memory_kv, persona_kv in ONE dispatch. 8 el/thread.
// ---------------------------------------------------------------------------
__global__ __launch_bounds__(256)
void cast_all(const float* __restrict__ x, const float* __restrict__ mem,
              const float* __restrict__ per, u16* __restrict__ ws) {
    int i = blockIdx.x * 256 + threadIdx.x;
    const float* src; u16* dst;
    if (i < 262144)           { src = x;   dst = ws + XBO;   }
    else if (i < 327680)      { src = mem; dst = ws + MEMBO; i -= 262144; }
    else if (i < 335872)      { src = per; dst = ws + PERBO; i -= 327680; }
    else return;
    const float4* p = reinterpret_cast<const float4*>(src) + (size_t)i * 2;
    float4 a = p[0], b = p[1];
    u16x4 o0, o1;
    o0[0] = f2bf(a.x); o0[1] = f2bf(a.y); o0[2] = f2bf(a.z); o0[3] = f2bf(a.w);
    o1[0] = f2bf(b.x); o1[1] = f2bf(b.y); o1[2] = f2bf(b.z); o1[3] = f2bf(b.w);
    u16x4* q = reinterpret_cast<u16x4*>(dst) + (size_t)i * 2;
    q[0] = o0; q[1] = o1;
}

// ---------------------------------------------------------------------------
// Wt[z][n][k] = W_z[k][n] as bf16 (transpose+cast), 64x64 LDS tiles, z = 0..3
// ---------------------------------------------------------------------------
__global__ __launch_bounds__(256)
void transp_cast(const float* __restrict__ w0, const float* __restrict__ w1,
                 const float* __restrict__ w2, const float* __restrict__ w3,
                 u16* __restrict__ wt) {
    __shared__ float t[64][65];
    const float* w = blockIdx.z == 0 ? w0 : blockIdx.z == 1 ? w1
                   : blockIdx.z == 2 ? w2 : w3;
    u16* o = wt + (size_t)blockIdx.z * (1024 * 1024);
    const int kt = blockIdx.y * 64, nt = blockIdx.x * 64;
    const int r = threadIdx.x >> 4, c4 = (threadIdx.x & 15) * 4;
#pragma unroll
    for (int p = 0; p < 4; p++) {
        float4 v = *reinterpret_cast<const float4*>(
            &w[(size_t)(kt + r + p * 16) * 1024 + nt + c4]);
        t[r + p * 16][c4 + 0] = v.x; t[r + p * 16][c4 + 1] = v.y;
        t[r + p * 16][c4 + 2] = v.z; t[r + p * 16][c4 + 3] = v.w;
    }
    __syncthreads();
#pragma unroll
    for (int p = 0; p < 4; p++) {
        int nn = r + p * 16;
        u16x4 ov;
        ov[0] = f2bf(t[c4 + 0][nn]); ov[1] = f2bf(t[c4 + 1][nn]);
        ov[2] = f2bf(t[c4 + 2][nn]); ov[3] = f2bf(t[c4 + 3][nn]);
        *reinterpret_cast<u16x4*>(&o[(size_t)(nt + nn) * 1024 + kt + c4]) = ov;
    }
}

// ---------------------------------------------------------------------------
// V transpose: VT[h*64+d][key] = V[key][h*64+d]. 64x64 LDS tiles.
// ---------------------------------------------------------------------------
__global__ __launch_bounds__(256)
void transp_v(u16* __restrict__ ws) {
    const int z = blockIdx.z;
    const int Skv = (z < 2) ? 2048 : (z == 2 ? 512 : 64);
    const int kb = blockIdx.x;
    if (kb * 64 >= Skv) return;
    const int h = blockIdx.y;
    const u16* V = ws + (z == 0 ? KVO + 2 * M1 : z == 1 ? KVO + 6 * M1
                       : z == 2 ? V2O : V3O);
    u16* VT = ws + (z == 0 ? XBO : z == 1 ? VT1O : z == 2 ? VT2O : VT3O);
    __shared__ __align__(16) u16 t[64][72];
    {
        const int r = threadIdx.x >> 3, c8 = (threadIdx.x & 7) * 8;
#pragma unroll
        for (int p = 0; p < 2; p++) {
            int rr = r + p * 32;
            bfrag v = *reinterpret_cast<const bfrag*>(
                &V[(size_t)(kb * 64 + rr) * 1024 + h * 64 + c8]);
            *reinterpret_cast<bfrag*>(&t[rr][c8]) = v;
        }
    }
    __syncthreads();
    {
        const int d = threadIdx.x & 63;
        const int k8b = (threadIdx.x >> 6) * 8;
#pragma unroll
        for (int p = 0; p < 2; p++) {
            int k8 = k8b + p * 32;
            bfrag o;
#pragma unroll
            for (int j = 0; j < 8; j++) o[j] = (short)t[k8 + j][d];
            *reinterpret_cast<bfrag*>(
                &VT[(size_t)(h * 64 + d) * Skv + kb * 64 + k8]) = o;
        }
    }
}

// ---------------------------------------------------------------------------
// 256x256 bf16 GEMM, fine-grained 4-slot pipeline: BK=32, 32 K-steps, ONE
// barrier per K-step. Stage for tile j+3 interleaved inside the two 16-MFMA
// phases of tile j; tile-boundary counted vmcnt(8) (drain 8->4->0 at tail).
// LDS 128KB = 4 slots x (A 256x32 + B 256x32). swz(r) = (r^(r>>2))&3 keeps
// ds_read_b128 frag reads conflict-free at the 64B row stride.
// ---------------------------------------------------------------------------
__global__ __launch_bounds__(512, 2)
void gemm256(const u16* __restrict__ A, const u16* __restrict__ Bt,
             u16* __restrict__ C, long sB, long sC, int scaleMask) {
    __shared__ __align__(16) u16 sa[4][256 * 32];
    __shared__ __align__(16) u16 sb[4][256 * 32];
    Bt += (size_t)blockIdx.z * sB;
    C  += (size_t)blockIdx.z * sC;
    const float scl = ((scaleMask >> blockIdx.z) & 1) ? SCALE_Q : 1.0f;
    const int tid = threadIdx.x;
    const int wid = tid >> 6, lane = tid & 63;
    const int lhi = lane >> 4, llo = lane & 15;
    const int wm = wid >> 2, wn = wid & 3;
    const int row0 = blockIdx.y * 256, col0 = blockIdx.x * 256;

    facc acc[8][4];
#pragma unroll
    for (int i = 0; i < 8; i++)
#pragma unroll
        for (int j = 0; j < 4; j++)
#pragma unroll
            for (int k = 0; k < 4; k++) acc[i][j][k] = 0.f;

    // per tile: A = 256x32 = 16KB = 1024 chunks of 16B; 512 thr -> 2 passes
    auto stageA = [&](int kt) {
        const int s = kt & 3, k0 = kt * 32;
#pragma unroll
        for (int pass = 0; pass < 2; pass++) {
            int i = pass * 512 + tid;
            int r = i >> 2, c = i & 3;
            int ck = c ^ ((r ^ (r >> 2)) & 3);        // inverse swizzle (source)
            gload16(&A[(size_t)(row0 + r) * 1024 + k0 + ck * 8],
                    &sa[s][(pass * 512 + wid * 64) * 8]);
        }
    };
    auto stageB = [&](int kt) {
        const int s = kt & 3, k0 = kt * 32;
#pragma unroll
        for (int pass = 0; pass < 2; pass++) {
            int i = pass * 512 + tid;
            int r = i >> 2, c = i & 3;
            int ck = c ^ ((r ^ (r >> 2)) & 3);
            gload16(&Bt[(size_t)(col0 + r) * 1024 + k0 + ck * 8],
                    &sb[s][(pass * 512 + wid * 64) * 8]);
        }
    };

    // prologue: T0,T1,T2 staged (12 loads); wait T0 (8 in flight)
    stageA(0); stageB(0);
    stageA(1); stageB(1);
    stageA(2); stageB(2);
    __builtin_amdgcn_sched_barrier(0);
    VMCNT(8);
    blockbar();

    for (int j = 0; j < 32; j++) {
        const int s = j & 3;
        const u16* pa = &sa[s][0];
        const u16* pb = &sb[s][0];
        const bool pre = (j + 3 < 32);
        // ---- phase 0: issue A-stage(j+3), B-frags + A-frags(mg0), 16 MFMA
        if (pre) stageA(j + 3);
        bfrag bf[4];
#pragma unroll
        for (int nf = 0; nf < 4; nf++) {
            int r = wn * 64 + nf * 16 + llo;
            int p = lhi ^ ((r ^ (r >> 2)) & 3);
            bf[nf] = *reinterpret_cast<const bfrag*>(&pb[r * 32 + p * 8]);
        }
        bfrag af[4];
#pragma unroll
        for (int mf = 0; mf < 4; mf++) {
            int r = wm * 128 + mf * 16 + llo;
            int p = lhi ^ ((r ^ (r >> 2)) & 3);
            af[mf] = *reinterpret_cast<const bfrag*>(&pa[r * 32 + p * 8]);
        }
        __builtin_amdgcn_s_setprio(1);
#pragma unroll
        for (int mf = 0; mf < 4; mf++)
#pragma unroll
            for (int nf = 0; nf < 4; nf++)
                acc[mf][nf] = __builtin_amdgcn_mfma_f32_16x16x32_bf16(
                    af[mf], bf[nf], acc[mf][nf], 0, 0, 0);
        __builtin_amdgcn_s_setprio(0);
        // ---- phase 1: issue B-stage(j+3), A-frags(mg1), 16 MFMA
        if (pre) stageB(j + 3);
#pragma unroll
        for (int mf = 0; mf < 4; mf++) {
            int r = wm * 128 + 64 + mf * 16 + llo;
            int p = lhi ^ ((r ^ (r >> 2)) & 3);
            af[mf] = *reinterpret_cast<const bfrag*>(&pa[r * 32 + p * 8]);
        }
        __builtin_amdgcn_s_setprio(1);
#pragma unroll
        for (int mf = 0; mf < 4; mf++)
#pragma unroll
            for (int nf = 0; nf < 4; nf++)
                acc[4 + mf][nf] = __builtin_amdgcn_mfma_f32_16x16x32_bf16(
                    af[mf], bf[nf], acc[4 + mf][nf], 0, 0, 0);
        __builtin_amdgcn_s_setprio(0);
        // ---- tile boundary: counted wait so T(j+1) is landed; keep rest flying
        if (j < 31) {
            __builtin_amdgcn_sched_barrier(0);
            if (pre)              VMCNT(8);   // T(j+2),T(j+3) in flight
            else if (j == 29)     VMCNT(4);   // T31 in flight
            else                  VMCNT(0);   // j == 30
            blockbar();
        }
    }

    // epilogue
#pragma unroll
    for (int mf8 = 0; mf8 < 8; mf8++) {
#pragma unroll
        for (int r = 0; r < 4; r++) {
            int row = row0 + wm * 128 + mf8 * 16 + lhi * 4 + r;
#pragma unroll
            for (int nf = 0; nf < 4; nf++) {
                int col = col0 + wn * 64 + nf * 16 + llo;
                C[(size_t)row * 1024 + col] = f2bf(acc[mf8][nf][r] * scl);
            }
        }
    }
}

// ---------------------------------------------------------------------------
// bf16 MFMA GEMM, m97 structure (kept for O-proj / mem / persona).
// ---------------------------------------------------------------------------
__global__ __launch_bounds__(256)
void gemm_bf16(const u16* __restrict__ A, const u16* __restrict__ Bt,
               u16* __restrict__ C, int M, long sA, long sB, long sC,
               int scaleMask) {
    __shared__ __align__(16) u16 sa[128 * 64];
    __shared__ __align__(16) u16 sb[128 * 64];
    A  += (size_t)blockIdx.z * sA;
    Bt += (size_t)blockIdx.z * sB;
    C  += (size_t)blockIdx.z * sC;
    const float scl = ((scaleMask >> blockIdx.z) & 1) ? SCALE_Q : 1.0f;
    const int tid = threadIdx.x;
    const int wid = tid >> 6, lane = tid & 63;
    const int lhi = lane >> 4, llo = lane & 15;
    const int wm = wid >> 1, wn = wid & 1;
    const int row0 = blockIdx.y * 128, col0 = blockIdx.x * 128;

    facc acc[4][4];
#pragma unroll
    for (int i = 0; i < 4; i++)
#pragma unroll
        for (int j = 0; j < 4; j++)
#pragma unroll
            for (int k = 0; k < 4; k++) acc[i][j][k] = 0.f;

    const int srow = lane >> 3, schunk = lane & 7;
    for (int kt = 0; kt < 16; kt++) {
        __syncthreads();
        const int k0 = kt * 64;
#pragma unroll
        for (int j = 0; j < 4; j++) {
            int r = wid * 32 + j * 8 + srow;
            int ck = schunk ^ (r & 7);
            int ar = row0 + r; if (ar > M - 1) ar = M - 1;   // clamp (M<128)
            gload16(&A[(size_t)ar * 1024 + k0 + ck * 8], &sa[(wid * 4 + j) * 512]);
            gload16(&Bt[(size_t)(col0 + r) * 1024 + k0 + ck * 8], &sb[(wid * 4 + j) * 512]);
        }
        __syncthreads();
#pragma unroll
        for (int ks = 0; ks < 2; ks++) {
            bfrag af[4], bfv[4];
#pragma unroll
            for (int mf = 0; mf < 4; mf++) {
                int r = wm * 64 + mf * 16 + llo;
                int p = (ks * 4 + lhi) ^ (r & 7);
                af[mf] = *reinterpret_cast<const bfrag*>(&sa[r * 64 + p * 8]);
            }
#pragma unroll
            for (int nf = 0; nf < 4; nf++) {
                int r = wn * 64 + nf * 16 + llo;
                int p = (ks * 4 + lhi) ^ (r & 7);
                bfv[nf] = *reinterpret_cast<const bfrag*>(&sb[r * 64 + p * 8]);
            }
            __builtin_amdgcn_s_setprio(1);
#pragma unroll
            for (int mf = 0; mf < 4; mf++)
#pragma unroll
                for (int nf = 0; nf < 4; nf++)
                    acc[mf][nf] = __builtin_amdgcn_mfma_f32_16x16x32_bf16(
                        af[mf], bfv[nf], acc[mf][nf], 0, 0, 0);
            __builtin_amdgcn_s_setprio(0);
        }
    }
#pragma unroll
    for (int mf = 0; mf < 4; mf++) {
#pragma unroll
        for (int r = 0; r < 4; r++) {
            int row = row0 + wm * 64 + mf * 16 + lhi * 4 + r;
            if (row < M) {
#pragma unroll
                for (int nf = 0; nf < 4; nf++) {
                    int col = col0 + wn * 64 + nf * 16 + llo;
                    C[(size_t)row * 1024 + col] = f2bf(acc[mf][nf][r] * scl);
                }
            }
        }
    }
}

// ---------------------------------------------------------------------------
// Merged attention, swapped-operand MFMA, fixed-shift softmax, and now a
// 4-slot fine pipeline: prefetch 3 K/VT tiles ahead via global_load_lds,
// ONE raw barrier + counted vmcnt(8/4/0) per tile (never drain mid-loop).
// Block mapping (1152 blocks, LPT) and split-KV unchanged from round 8.
// ---------------------------------------------------------------------------
__global__ __launch_bounds__(256)
void attn_tiled(u16* __restrict__ ws) {
    __shared__ __align__(16) u16 ksm[4][64 * 64];
    __shared__ __align__(16) u16 vtm[4][64 * 64];
    __shared__ __align__(16) u16 psm[4][16][72];

    const int blk = blockIdx.x;
    int branch, h, qb, pair = 0, half = 0;
    bool partial = false;
    if (blk < 256) {
        pair = blk >> 1; half = blk & 1;
        qb = 15 - (pair >> 4); h = pair & 15;       // qb 8..15
        branch = 1; partial = true;
    } else if (blk < 384) { int t = blk - 256; branch = 1; qb = 7 - (t >> 4);  h = t & 15; }
    else if (blk < 640)   { int t = blk - 384; branch = 0; qb = 15 - (t >> 4); h = t & 15; }
    else if (blk < 896)   { int t = blk - 640; branch = 2; qb = t >> 4;        h = t & 15; }
    else                  { int t = blk - 896; branch = 3; qb = t >> 4;        h = t & 15; }

    size_t kb_, vb_; int Skv, maskMode;
    if (branch == 0)      { kb_ = KVO;          vb_ = XBO;  Skv = 2048; maskMode = 2; }
    else if (branch == 1) { kb_ = KVO + 4 * M1; vb_ = VT1O; Skv = 2048; maskMode = 1; }
    else if (branch == 2) { kb_ = K2O;          vb_ = VT2O; Skv = 512;  maskMode = 0; }
    else                  { kb_ = K3O;          vb_ = VT3O; Skv = 64;   maskMode = 0; }
    const u16* Kp  = ws + kb_;
    const u16* VTp = ws + vb_;
    u16* Qp = ws + QO + (size_t)branch * 2 * M1;

    const int tid = threadIdx.x, wid = tid >> 6, lane = tid & 63;
    const int llo = lane & 15, lhi = lane >> 4;
    const int q0 = qb * 128;
    const int qw = q0 + wid * 32;          // this wave's 32 q rows
    const int hoff = h * 64;

    // tile range for this block
    int tBeg, tEnd;
    if (partial) {
        int n = qb + 1;                    // half size; total = 2qb+2
        tBeg = half * n; tEnd = tBeg + n;
    } else {
        tEnd = maskMode ? (qb * 2 + 2) : (Skv >> 6);
        tBeg = (maskMode == 2 && q0 >= WIN) ? ((q0 - WIN) >> 6) : 0;
    }
    // per-wave clip (skips fully-masked tiles; also avoids masked-tile hazard)
    int myBeg = tBeg, myEnd = tEnd;
    if (maskMode) { int e = ((qw + 31) >> 6) + 1; if (e < myEnd) myEnd = e; }
    if (maskMode == 2 && qw >= WIN) { int b = (qw - WIN) >> 6; if (b > myBeg) myBeg = b; }

    bfrag qf[2][2];
#pragma unroll
    for (int sub = 0; sub < 2; sub++)
#pragma unroll
        for (int ds = 0; ds < 2; ds++)
            qf[sub][ds] = *reinterpret_cast<const bfrag*>(
                &Qp[(size_t)(qw + sub * 16 + llo) * 1024 + hoff + ds * 32 + lhi * 8]);

    facc ot[2][4];
    float lsum[2] = {0.f, 0.f};
#pragma unroll
    for (int sub = 0; sub < 2; sub++)
#pragma unroll
        for (int db = 0; db < 4; db++)
#pragma unroll
            for (int k = 0; k < 4; k++) ot[sub][db][k] = 0.f;

    const int srow = lane >> 3, schunk = lane & 7;
    auto stage = [&](int kt) {
        const int s = kt & 3;
#pragma unroll
        for (int j = 0; j < 2; j++) {
            int r = wid * 16 + j * 8 + srow;                 // tile row 0..63
            int ck = schunk ^ (r & 7);                       // inverse swizzle
            gload16(&Kp[(size_t)(kt * 64 + r) * 1024 + hoff + ck * 8],
                    &ksm[s][(wid * 2 + j) * 512]);
            gload16(&VTp[(size_t)(hoff + r) * Skv + kt * 64 + ck * 8],
                    &vtm[s][(wid * 2 + j) * 512]);
        }
    };

    // prologue: stage up to 3 tiles; counted wait so T(tBeg) is landed
    const int nt = tEnd - tBeg;
    stage(tBeg);
    if (nt > 1) stage(tBeg + 1);
    if (nt > 2) stage(tBeg + 2);
    __builtin_amdgcn_sched_barrier(0);
    if (nt > 2)      VMCNT(8);
    else if (nt > 1) VMCNT(4);
    else             VMCNT(0);
    blockbar();

    for (int kt = tBeg; kt < tEnd; kt++) {
        const int s = kt & 3;
        if (kt + 3 < tEnd) stage(kt + 3);    // flies under this tile's compute

        if (kt >= myBeg && kt < myEnd) {     // wave-uniform clip
            bfrag kf[4][2], vf[4][2];
#pragma unroll
            for (int nf = 0; nf < 4; nf++)
#pragma unroll
                for (int ds = 0; ds < 2; ds++) {
                    int r = nf * 16 + llo;
                    int p = (ds * 4 + lhi) ^ (r & 7);
                    kf[nf][ds] = *reinterpret_cast<const bfrag*>(
                        &ksm[s][r * 64 + p * 8]);
                }
#pragma unroll
            for (int db = 0; db < 4; db++)
#pragma unroll
                for (int ks = 0; ks < 2; ks++) {
                    int d = db * 16 + llo;
                    int p = (ks * 4 + lhi) ^ (d & 7);
                    vf[db][ks] = *reinterpret_cast<const bfrag*>(
                        &vtm[s][d * 64 + p * 8]);
                }

#pragma unroll
            for (int sub = 0; sub < 2; sub++) {
                const int qsb = qw + sub * 16;         // lane qi = qsb + llo
                facc st[4];
#pragma unroll
                for (int nf = 0; nf < 4; nf++)
#pragma unroll
                    for (int k = 0; k < 4; k++) st[nf][k] = 0.f;
                __builtin_amdgcn_s_setprio(1);
#pragma unroll
                for (int nf = 0; nf < 4; nf++)
#pragma unroll
                    for (int ds = 0; ds < 2; ds++)
                        st[nf] = __builtin_amdgcn_mfma_f32_16x16x32_bf16(
                            kf[nf][ds], qf[sub][ds], st[nf], 0, 0, 0);
                __builtin_amdgcn_s_setprio(0);

                float sarr[16];
#pragma unroll
                for (int nf = 0; nf < 4; nf++)
#pragma unroll
                    for (int r = 0; r < 4; r++) sarr[nf * 4 + r] = st[nf][r];

                const bool needC = maskMode && (kt * 64 + 63 > qsb);
                const bool needW = (maskMode == 2) && (kt * 64 < qsb + 15 - WIN);
                if (needC || needW) {
                    const int qi = qsb + llo;
#pragma unroll
                    for (int nf = 0; nf < 4; nf++)
#pragma unroll
                        for (int r = 0; r < 4; r++) {
                            int key = kt * 64 + nf * 16 + lhi * 4 + r;
                            if ((needC && key > qi) || (needW && (qi - key) > WIN))
                                sarr[nf * 4 + r] = -1e30f;
                        }
                }
                // fixed-shift softmax: P = exp2(s - 16); l accumulates
                float p[16];
#pragma unroll
                for (int i = 0; i < 16; i++)
                    p[i] = __builtin_amdgcn_exp2f(sarr[i] - SM_SHIFT);
#pragma unroll
                for (int i = 0; i < 16; i++) lsum[sub] += p[i];

                // P^T -> per-wave LDS (cvt_pk b32 writes), then b128 frags
#pragma unroll
                for (int nf = 0; nf < 4; nf++)
#pragma unroll
                    for (int rp = 0; rp < 2; rp++) {
                        u32 w = cvt_pk(p[nf * 4 + rp * 2], p[nf * 4 + rp * 2 + 1]);
                        *reinterpret_cast<u32*>(
                            &psm[wid][llo][nf * 16 + lhi * 4 + rp * 2]) = w;
                    }
                bfrag pf0 = *reinterpret_cast<const bfrag*>(&psm[wid][llo][lhi * 8]);
                bfrag pf1 = *reinterpret_cast<const bfrag*>(&psm[wid][llo][32 + lhi * 8]);
                __builtin_amdgcn_s_setprio(1);
#pragma unroll
                for (int db = 0; db < 4; db++) {
                    ot[sub][db] = __builtin_amdgcn_mfma_f32_16x16x32_bf16(
                        vf[db][0], pf0, ot[sub][db], 0, 0, 0);
                    ot[sub][db] = __builtin_amdgcn_mfma_f32_16x16x32_bf16(
                        vf[db][1], pf1, ot[sub][db], 0, 0, 0);
                }
                __builtin_amdgcn_s_setprio(0);
            }
        }
        // tile boundary: counted wait so T(kt+1) is landed; keep rest flying
        if (kt + 1 < tEnd) {
            __builtin_amdgcn_sched_barrier(0);
            if (kt + 3 < tEnd)      VMCNT(8);
            else if (kt + 2 < tEnd) VMCNT(4);
            else                    VMCNT(0);
            blockbar();
        }
    }

    if (!partial) {
        // epilogue: reduce l, normalize, write O^T -> O[q][d] in-place over Q
#pragma unroll
        for (int sub = 0; sub < 2; sub++) {
            float l = lsum[sub];
            l += __shfl_xor(l, 16);
            l += __shfl_xor(l, 32);
            float inv = 1.f / l;
            u16* orow = &Qp[(size_t)(qw + sub * 16 + llo) * 1024 + hoff];
#pragma unroll
            for (int db = 0; db < 4; db++) {
                u16x4 pk;
#pragma unroll
                for (int r = 0; r < 4; r++) pk[r] = f2bf(ot[sub][db][r] * inv);
                *reinterpret_cast<u16x4*>(&orow[db * 16 + lhi * 4]) = pk;
            }
        }
    } else {
        // write f32 partial record (O^T raw + per-row l) for combine_split
        float* rec = reinterpret_cast<float*>(ws) + (size_t)(pair * 2 + half) * RECSZ;
#pragma unroll
        for (int sub = 0; sub < 2; sub++) {
            float l = lsum[sub];
            l += __shfl_xor(l, 16);
            l += __shfl_xor(l, 32);
            rec[8192 + sub * 256 + tid] = l;
#pragma unroll
            for (int db = 0; db < 4; db++)
                *reinterpret_cast<facc*>(&rec[tid * 32 + sub * 16 + db * 4]) =
                    ot[sub][db];
        }
    }
}

// ---------------------------------------------------------------------------
// Combine split-KV halves: O = (O0 + O1) / (l0 + l1), write into Q1 region.
// ---------------------------------------------------------------------------
__global__ __launch_bounds__(256)
void combine_split(u16* __restrict__ ws) {
    const int pair = blockIdx.x;                 // 0..127
    const int qb = 15 - (pair >> 4), h = pair & 15;
    const int tid = threadIdx.x, wid = tid >> 6, lane = tid & 63;
    const int llo = lane & 15, lhi = lane >> 4;
    const float* r0 = reinterpret_cast<const float*>(ws) + (size_t)(pair * 2) * RECSZ;
    const float* r1 = r0 + RECSZ;
    u16* Qp = ws + QO + 2 * M1;                  // branch 1 (long-causal)
    const int qw = qb * 128 + wid * 32;
#pragma unroll
    for (int sub = 0; sub < 2; sub++) {
        float inv = 1.f / (r0[8192 + sub * 256 + tid] + r1[8192 + sub * 256 + tid]);
        u16* orow = &Qp[(size_t)(qw + sub * 16 + llo) * 1024 + h * 64];
#pragma unroll
        for (int db = 0; db < 4; db++) {
            u16x4 pk;
#pragma unroll
            for (int r = 0; r < 4; r++) {
                float v = r0[tid * 32 + sub * 16 + db * 4 + r] +
                          r1[tid * 32 + sub * 16 + db * 4 + r];
                pk[r] = f2bf(v * inv);
            }
            *reinterpret_cast<u16x4*>(&orow[db * 16 + lhi * 4]) = pk;
        }
    }
}

// ---------------------------------------------------------------------------
// Gate + fuse (out4 bf16, stride 2M): g = softmax(concat @ gate_w + gate_b).
// ---------------------------------------------------------------------------
__global__ __launch_bounds__(256)
void gate_fuse(const u16* __restrict__ o4, const float* __restrict__ gw,
               const float* __restrict__ gb, float* __restrict__ out) {
    const int s = blockIdx.x, tid = threadIdx.x;
    const u16* ob0 = o4 + (size_t)s * H;
    float p[4] = {0.f, 0.f, 0.f, 0.f};
    for (int b = 0; b < 4; b++) {
        const u16* obb = ob0 + b * 2 * M1;
        const float* gwb = gw + (size_t)b * H * 4;
        for (int i = tid; i < H; i += 256) {
            float xv = bf2f(obb[i]);
            float4 g4 = *reinterpret_cast<const float4*>(&gwb[(size_t)i * 4]);
            p[0] += xv * g4.x; p[1] += xv * g4.y;
            p[2] += xv * g4.z; p[3] += xv * g4.w;
        }
    }
#pragma unroll
    for (int off = 1; off < 64; off <<= 1)
#pragma unroll
        for (int j = 0; j < 4; j++) p[j] += __shfl_xor(p[j], off);
    __shared__ float red[4][4];
    if ((tid & 63) == 0) {
        int w = tid >> 6;
#pragma unroll
        for (int j = 0; j < 4; j++) red[w][j] = p[j];
    }
    __syncthreads();
    float gl[4];
#pragma unroll
    for (int j = 0; j < 4; j++)
        gl[j] = gb[j] + red[0][j] + red[1][j] + red[2][j] + red[3][j];
    float mx = fmaxf(fmaxf(gl[0], gl[1]), fmaxf(gl[2], gl[3]));
    float e[4]; float tot = 0.f;
#pragma unroll
    for (int j = 0; j < 4; j++) { e[j] = __expf(gl[j] - mx); tot += e[j]; }
    float inv = 1.f / tot;
    int d = tid * 4;
    float4 rv; rv.x = rv.y = rv.z = rv.w = 0.f;
#pragma unroll
    for (int b = 0; b < 4; b++) {
        const u16* obb = ob0 + b * 2 * M1 + d;
        float wgt = e[b] * inv;
        rv.x += wgt * bf2f(obb[0]);
        rv.y += wgt * bf2f(obb[1]);
        rv.z += wgt * bf2f(obb[2]);
        rv.w += wgt * bf2f(obb[3]);
    }
    *reinterpret_cast<float4*>(&out[(size_t)s * H + d]) = rv;
}

// ---------------------------------------------------------------------------
// Orchestration.
// ---------------------------------------------------------------------------
extern "C" void kernel_launch(void* const* d_in, const int* in_sizes, int n_in,
                              void* d_out, int out_size, void* d_ws, size_t ws_size,
                              hipStream_t stream) {
    const float* Wm[16];
    for (int i = 0; i < 16; i++) Wm[i] = (const float*)d_in[i];
    const float* gw = (const float*)d_in[16];
    const float* gb = (const float*)d_in[17];
    const float* x = (const float*)d_in[18];
    const float* mem = (const float*)d_in[19];
    const float* per = (const float*)d_in[20];
    float* out = (float*)d_out;
    u16* ws = (u16*)d_ws;

    dim3 blk(256);
    cast_all<<<dim3(1312), blk, 0, stream>>>(x, mem, per, ws);

    // Phase A: Q0..Q3 (x SCALE_Q), K0,V0,K1,V1 -- 256^2 fine-pipelined GEMM
    transp_cast<<<dim3(16, 16, 4), blk, 0, stream>>>(
        Wm[0], Wm[4], Wm[8], Wm[12], ws + WTO);            // wq x4
    transp_cast<<<dim3(16, 16, 4), blk, 0, stream>>>(
        Wm[1], Wm[2], Wm[5], Wm[6], ws + WTO + 4 * M1);    // wk0,wv0,wk1,wv1
    gemm256<<<dim3(4, 8, 8), dim3(512), 0, stream>>>(
        ws + XBO, ws + WTO, ws + QO, (long)M1, (long)(2 * M1), 0xF);

    // Phase B: mem/persona K,V
    transp_cast<<<dim3(16, 16, 4), blk, 0, stream>>>(
        Wm[9], Wm[10], Wm[13], Wm[14], ws + WTO);          // wk2,wv2,wk3,wv3
    gemm_bf16<<<dim3(8, 4, 2), blk, 0, stream>>>(
        ws + MEMBO, ws + WTO, ws + K2O, 512, 0, (long)M1, (long)(M1 >> 1), 0);
    gemm_bf16<<<dim3(8, 1, 2), blk, 0, stream>>>(
        ws + PERBO, ws + WTO + 2 * M1, ws + K3O, 64, 0, (long)M1, (long)(M1 >> 4), 0);

    // Phase C: V transposes (VT0 overlays XB), merged attention, split-combine
    transp_v<<<dim3(32, 16, 4), blk, 0, stream>>>(ws);
    attn_tiled<<<dim3(1152), blk, 0, stream>>>(ws);
    combine_split<<<dim3(128), blk, 0, stream>>>(ws);

    // Phase D: O-projection (transp_cast overwrites WTO only after combine)
    transp_cast<<<dim3(16, 16, 4), blk, 0, stream>>>(
        Wm[3], Wm[7], Wm[11], Wm[15], ws + WTO);           // wo x4
    gemm_bf16<<<dim3(8, 16, 4), blk, 0, stream>>>(
        ws + QO, ws + WTO, ws + KVO, 2048, (long)(2 * M1), (long)M1,
        (long)(2 * M1), 0);

    // Phase E
    gate_fuse<<<dim3(S), blk, 0, stream>>>(ws + KVO, gw, gb, out);
}

// Round 11
// 174.264 us; speedup vs baseline: 1.1953x; 1.1953x over previous
//
#include <hip/hip_runtime.h>

#define S 2048
#define H 1024
#define NH 16
#define HD 64
#define WIN 512
// Q pre-scale: (1/sqrt(64)) * log2(e)  -> scores arrive in log2 domain
#define SCALE_Q 0.18033688f
#define SM_SHIFT 16.0f

typedef unsigned short u16;
typedef unsigned int u32;
typedef __attribute__((ext_vector_type(8))) short bfrag;   // 8 bf16 (4 VGPRs)
typedef __attribute__((ext_vector_type(4))) float facc;    // 4 f32 acc
typedef __attribute__((ext_vector_type(4))) unsigned short u16x4;

#define VMCNT(n) asm volatile("s_waitcnt vmcnt(" #n ")" ::: "memory")

// ---- workspace layout (u16 elements), total 30.25M el = 60.5 MB ------------
constexpr size_t M1    = 1u << 20;
constexpr size_t WTO   = 0;                      // 8M  weights / split partials
constexpr size_t XBO   = 8 * M1;                 // 2M  x bf16; later VT0
constexpr size_t MEMBO = 10 * M1;                // 0.5M
constexpr size_t PERBO = MEMBO + (M1 >> 1);      // 64K
constexpr size_t QO    = PERBO + (M1 >> 4);      // 8M  Q0..Q3 (2M each)
constexpr size_t KVO   = QO + 8 * M1;            // 8M  K0,V0,K1,V1; later out4
constexpr size_t K2O   = KVO + 8 * M1;           // 0.5M
constexpr size_t V2O   = K2O + (M1 >> 1);        // 0.5M
constexpr size_t K3O   = V2O + (M1 >> 1);        // 64K
constexpr size_t V3O   = K3O + (M1 >> 4);        // 64K
constexpr size_t VT1O  = V3O + (M1 >> 4);        // 2M
constexpr size_t VT2O  = VT1O + 2 * M1;          // 0.5M
constexpr size_t VT3O  = VT2O + (M1 >> 1);       // 64K
// split-KV partial records: 256 x 8704 f32 = 8.9 MB, overlay WTO
constexpr size_t RECSZ = 8704;

__device__ __forceinline__ u16 f2bf(float f) {
    union { float f; unsigned u; } v; v.f = f;
    unsigned r = v.u + 0x7fffu + ((v.u >> 16) & 1u);   // RNE
    return (u16)(r >> 16);
}
__device__ __forceinline__ float bf2f(u16 b) {
    union { unsigned u; float f; } v; v.u = ((unsigned)b) << 16;
    return v.f;
}
__device__ __forceinline__ void gload16(const u16* g, u16* l) {
    __builtin_amdgcn_global_load_lds(
        (const __attribute__((address_space(1))) u32*)g,
        (__attribute__((address_space(3))) u32*)l, 16, 0, 0);
}
__device__ __forceinline__ u32 cvt_pk(float a, float b) {
    u32 w;
    asm("v_cvt_pk_bf16_f32 %0, %1, %2" : "=v"(w) : "v"(a), "v"(b));
    return w;
}
// raw workgroup barrier with compiler memory fence (NO vmcnt drain)
__device__ __forceinline__ void blockbar() {
    __builtin_amdgcn_sched_barrier(0);
    asm volatile("" ::: "memory");
    __builtin_amdgcn_s_barrier();
    asm volatile("" ::: "memory");
    __builtin_amdgcn_sched_barrier(0);
}

// ---------------------------------------------------------------------------
// fp32 -> bf16 cast of x, memory_kv, persona_kv in ONE dispatch. 8 el/thread.
// ---------------------------------------------------------------------------
__global__ __launch_bounds__(256)
void cast_all(const float* __restrict__ x, const float* __restrict__ mem,
              const float* __restrict__ per, u16* __restrict__ ws) {
    int i = blockIdx.x * 256 + threadIdx.x;
    const float* src; u16* dst;
    if (i < 262144)           { src = x;   dst = ws + XBO;   }
    else if (i < 327680)      { src = mem; dst = ws + MEMBO; i -= 262144; }
    else if (i < 335872)      { src = per; dst = ws + PERBO; i -= 327680; }
    else return;
    const float4* p = reinterpret_cast<const float4*>(src) + (size_t)i * 2;
    float4 a = p[0], b = p[1];
    u16x4 o0, o1;
    o0[0] = f2bf(a.x); o0[1] = f2bf(a.y); o0[2] = f2bf(a.z); o0[3] = f2bf(a.w);
    o1[0] = f2bf(b.x); o1[1] = f2bf(b.y); o1[2] = f2bf(b.z); o1[3] = f2bf(b.w);
    u16x4* q = reinterpret_cast<u16x4*>(dst) + (size_t)i * 2;
    q[0] = o0; q[1] = o1;
}

// ---------------------------------------------------------------------------
// Wt[z][n][k] = W_z[k][n] as bf16 (transpose+cast), up to 8 weights/dispatch.
// ---------------------------------------------------------------------------
__global__ __launch_bounds__(256)
void transp_cast8(const float* __restrict__ w0, const float* __restrict__ w1,
                  const float* __restrict__ w2, const float* __restrict__ w3,
                  const float* __restrict__ w4, const float* __restrict__ w5,
                  const float* __restrict__ w6, const float* __restrict__ w7,
                  u16* __restrict__ wt) {
    __shared__ float t[64][65];
    const float* wp[8] = {w0, w1, w2, w3, w4, w5, w6, w7};
    const float* w = wp[blockIdx.z];
    u16* o = wt + (size_t)blockIdx.z * (1024 * 1024);
    const int kt = blockIdx.y * 64, nt = blockIdx.x * 64;
    const int r = threadIdx.x >> 4, c4 = (threadIdx.x & 15) * 4;
#pragma unroll
    for (int p = 0; p < 4; p++) {
        float4 v = *reinterpret_cast<const float4*>(
            &w[(size_t)(kt + r + p * 16) * 1024 + nt + c4]);
        t[r + p * 16][c4 + 0] = v.x; t[r + p * 16][c4 + 1] = v.y;
        t[r + p * 16][c4 + 2] = v.z; t[r + p * 16][c4 + 3] = v.w;
    }
    __syncthreads();
#pragma unroll
    for (int p = 0; p < 4; p++) {
        int nn = r + p * 16;
        u16x4 ov;
        ov[0] = f2bf(t[c4 + 0][nn]); ov[1] = f2bf(t[c4 + 1][nn]);
        ov[2] = f2bf(t[c4 + 2][nn]); ov[3] = f2bf(t[c4 + 3][nn]);
        *reinterpret_cast<u16x4*>(&o[(size_t)(nt + nn) * 1024 + kt + c4]) = ov;
    }
}

// ---------------------------------------------------------------------------
// V transpose: VT[h*64+d][key] = V[key][h*64+d]. 64x64 LDS tiles.
// ---------------------------------------------------------------------------
__global__ __launch_bounds__(256)
void transp_v(u16* __restrict__ ws) {
    const int z = blockIdx.z;
    const int Skv = (z < 2) ? 2048 : (z == 2 ? 512 : 64);
    const int kb = blockIdx.x;
    if (kb * 64 >= Skv) return;
    const int h = blockIdx.y;
    const u16* V = ws + (z == 0 ? KVO + 2 * M1 : z == 1 ? KVO + 6 * M1
                       : z == 2 ? V2O : V3O);
    u16* VT = ws + (z == 0 ? XBO : z == 1 ? VT1O : z == 2 ? VT2O : VT3O);
    __shared__ __align__(16) u16 t[64][72];
    {
        const int r = threadIdx.x >> 3, c8 = (threadIdx.x & 7) * 8;
#pragma unroll
        for (int p = 0; p < 2; p++) {
            int rr = r + p * 32;
            bfrag v = *reinterpret_cast<const bfrag*>(
                &V[(size_t)(kb * 64 + rr) * 1024 + h * 64 + c8]);
            *reinterpret_cast<bfrag*>(&t[rr][c8]) = v;
        }
    }
    __syncthreads();
    {
        const int d = threadIdx.x & 63;
        const int k8b = (threadIdx.x >> 6) * 8;
#pragma unroll
        for (int p = 0; p < 2; p++) {
            int k8 = k8b + p * 32;
            bfrag o;
#pragma unroll
            for (int j = 0; j < 8; j++) o[j] = (short)t[k8 + j][d];
            *reinterpret_cast<bfrag*>(
                &VT[(size_t)(h * 64 + d) * Skv + kb * 64 + k8]) = o;
        }
    }
}

// ---------------------------------------------------------------------------
// 256x256 bf16 GEMM, faithful 8-phase schedule (T3+T4+T5), BK=64:
// 2 one-K-tile LDS buffers (64KB each). Per tile j, 4 phases; phase q:
//   ds_read: B-frags (8, q==0 only) + A-frags for acc rows 2q,2q+1 (4)
//   stage ONE unit of tile j+1: q0->B rows 0..127, q1->B rows 128..255,
//     q2->A {(r&127)<64}, q3->A {(r&127)>=64}     (2 gload16/thread each)
//   barrier; lgkmcnt(0); setprio(1); 16 MFMA; setprio(0);
//   close: q==1 -> vmcnt(4) [A-g23 landed], q==3 -> vmcnt(2) [B+A-g01
//     landed, A-g23 still in flight]; barrier.  Never vmcnt(0) mid-loop.
// 8-slot chunk-XOR swizzle (128B rows) = 0 bank conflicts (r8/r9 verified).
// ---------------------------------------------------------------------------
__global__ __launch_bounds__(512, 2)
void gemm256(const u16* __restrict__ A, const u16* __restrict__ Bt,
             u16* __restrict__ C, long sB, long sC, int scaleMask) {
    __shared__ __align__(16) u16 sa[2][256 * 64];
    __shared__ __align__(16) u16 sb[2][256 * 64];
    Bt += (size_t)blockIdx.z * sB;
    C  += (size_t)blockIdx.z * sC;
    const float scl = ((scaleMask >> blockIdx.z) & 1) ? SCALE_Q : 1.0f;
    const int tid = threadIdx.x;
    const int wid = tid >> 6, lane = tid & 63;
    const int lhi = lane >> 4, llo = lane & 15;
    const int wm = wid >> 2, wn = wid & 3;        // 2M x 4N waves
    const int row0 = blockIdx.y * 256, col0 = blockIdx.x * 256;

    facc acc[8][4];
#pragma unroll
    for (int i = 0; i < 8; i++)
#pragma unroll
        for (int j = 0; j < 4; j++)
#pragma unroll
            for (int k = 0; k < 4; k++) acc[i][j][k] = 0.f;

    // stage B half h (rows h*128..h*128+127) of K-tile kt -> buf kt&1
    auto stageB = [&](int kt, int h) {
        const int b = kt & 1, k0 = kt * 64;
#pragma unroll
        for (int pass = 0; pass < 2; pass++) {
            int i = pass * 512 + tid;               // chunk 0..1023 in half
            int r = h * 128 + (i >> 3);
            int ck = (i & 7) ^ (r & 7);             // inverse swizzle (source)
            gload16(&Bt[(size_t)(col0 + r) * 1024 + k0 + ck * 8],
                    &sb[b][(size_t)(h * 1024 + pass * 512 + wid * 64) * 8]);
        }
    };
    // stage A group g (rows with (r&127) in [g*64,g*64+64)) of K-tile kt
    auto stageAg = [&](int kt, int g) {
        const int b = kt & 1, k0 = kt * 64;
#pragma unroll
        for (int pass = 0; pass < 2; pass++) {
            int i = pass * 512 + tid;
            int i8 = i >> 3;                        // row ordinal 0..127
            int r = g * 64 + (i8 & 63) + (i8 >> 6) * 128;
            int ck = (i & 7) ^ (r & 7);
            int b8 = (pass * 512 + wid * 64) >> 3;  // wave base ordinal
            int rb = g * 64 + (b8 & 63) + (b8 >> 6) * 128;
            gload16(&A[(size_t)(row0 + r) * 1024 + k0 + ck * 8],
                    &sa[b][(size_t)rb * 64]);
        }
    };

    // prologue: tile 0 fully staged; wait all but A-g23 (covered at q==1 close)
    stageB(0, 0); stageB(0, 1); stageAg(0, 0); stageAg(0, 1);
    __builtin_amdgcn_sched_barrier(0);
    VMCNT(2);
    blockbar();

    for (int j = 0; j < 16; j++) {
        const int b = j & 1;
        const u16* pa = &sa[b][0];
        const u16* pb = &sb[b][0];
        bfrag bf[4][2];
#pragma unroll
        for (int q = 0; q < 4; q++) {
            if (q == 0) {
#pragma unroll
                for (int nf = 0; nf < 4; nf++)
#pragma unroll
                    for (int ks = 0; ks < 2; ks++) {
                        int r = wn * 64 + nf * 16 + llo;
                        int p = (ks * 4 + lhi) ^ (r & 7);
                        bf[nf][ks] = *reinterpret_cast<const bfrag*>(
                            &pb[r * 64 + p * 8]);
                    }
            }
            bfrag af[2][2];
#pragma unroll
            for (int rr = 0; rr < 2; rr++)
#pragma unroll
                for (int ks = 0; ks < 2; ks++) {
                    int r = wm * 128 + (q * 2 + rr) * 16 + llo;
                    int p = (ks * 4 + lhi) ^ (r & 7);
                    af[rr][ks] = *reinterpret_cast<const bfrag*>(
                        &pa[r * 64 + p * 8]);
                }
            if (j < 15) {
                if (q == 0)      stageB(j + 1, 0);
                else if (q == 1) stageB(j + 1, 1);
                else if (q == 2) stageAg(j + 1, 0);
                else             stageAg(j + 1, 1);
            }
            blockbar();
            asm volatile("s_waitcnt lgkmcnt(0)" ::: "memory");
            __builtin_amdgcn_sched_barrier(0);
            __builtin_amdgcn_s_setprio(1);
#pragma unroll
            for (int rr = 0; rr < 2; rr++)
#pragma unroll
                for (int nf = 0; nf < 4; nf++)
#pragma unroll
                    for (int ks = 0; ks < 2; ks++)
                        acc[q * 2 + rr][nf] = __builtin_amdgcn_mfma_f32_16x16x32_bf16(
                            af[rr][ks], bf[nf][ks], acc[q * 2 + rr][nf], 0, 0, 0);
            __builtin_amdgcn_s_setprio(0);
            // phase close: counted waits certify NEXT reads, then barrier
            __builtin_amdgcn_sched_barrier(0);
            if (q == 1) { if (j < 15) { VMCNT(4); } else { VMCNT(0); } }
            else if (q == 3 && j < 15) { VMCNT(2); }
            blockbar();
        }
    }

    // epilogue
#pragma unroll
    for (int mf = 0; mf < 8; mf++) {
#pragma unroll
        for (int r = 0; r < 4; r++) {
            int row = row0 + wm * 128 + mf * 16 + lhi * 4 + r;
#pragma unroll
            for (int nf = 0; nf < 4; nf++) {
                int col = col0 + wn * 64 + nf * 16 + llo;
                C[(size_t)row * 1024 + col] = f2bf(acc[mf][nf][r] * scl);
            }
        }
    }
}

// ---------------------------------------------------------------------------
// 128x128 m97-structure GEMM body (shared by gemm_bf16 and gemm_small).
// ---------------------------------------------------------------------------
__device__ __forceinline__ void gemm128_body(
    const u16* __restrict__ A, const u16* __restrict__ Bt, u16* __restrict__ C,
    int M, float scl, u16* sa, u16* sb, int row0, int col0) {
    const int tid = threadIdx.x;
    const int wid = tid >> 6, lane = tid & 63;
    const int lhi = lane >> 4, llo = lane & 15;
    const int wm = wid >> 1, wn = wid & 1;

    facc acc[4][4];
#pragma unroll
    for (int i = 0; i < 4; i++)
#pragma unroll
        for (int j = 0; j < 4; j++)
#pragma unroll
            for (int k = 0; k < 4; k++) acc[i][j][k] = 0.f;

    const int srow = lane >> 3, schunk = lane & 7;
    for (int kt = 0; kt < 16; kt++) {
        __syncthreads();
        const int k0 = kt * 64;
#pragma unroll
        for (int j = 0; j < 4; j++) {
            int r = wid * 32 + j * 8 + srow;
            int ck = schunk ^ (r & 7);
            int ar = row0 + r; if (ar > M - 1) ar = M - 1;   // clamp (M<128)
            gload16(&A[(size_t)ar * 1024 + k0 + ck * 8], &sa[(wid * 4 + j) * 512]);
            gload16(&Bt[(size_t)(col0 + r) * 1024 + k0 + ck * 8], &sb[(wid * 4 + j) * 512]);
        }
        __syncthreads();
#pragma unroll
        for (int ks = 0; ks < 2; ks++) {
            bfrag af[4], bfv[4];
#pragma unroll
            for (int mf = 0; mf < 4; mf++) {
                int r = wm * 64 + mf * 16 + llo;
                int p = (ks * 4 + lhi) ^ (r & 7);
                af[mf] = *reinterpret_cast<const bfrag*>(&sa[r * 64 + p * 8]);
            }
#pragma unroll
            for (int nf = 0; nf < 4; nf++) {
                int r = wn * 64 + nf * 16 + llo;
                int p = (ks * 4 + lhi) ^ (r & 7);
                bfv[nf] = *reinterpret_cast<const bfrag*>(&sb[r * 64 + p * 8]);
            }
            __builtin_amdgcn_s_setprio(1);
#pragma unroll
            for (int mf = 0; mf < 4; mf++)
#pragma unroll
                for (int nf = 0; nf < 4; nf++)
                    acc[mf][nf] = __builtin_amdgcn_mfma_f32_16x16x32_bf16(
                        af[mf], bfv[nf], acc[mf][nf], 0, 0, 0);
            __builtin_amdgcn_s_setprio(0);
        }
    }
#pragma unroll
    for (int mf = 0; mf < 4; mf++) {
#pragma unroll
        for (int r = 0; r < 4; r++) {
            int row = row0 + wm * 64 + mf * 16 + lhi * 4 + r;
            if (row < M) {
#pragma unroll
                for (int nf = 0; nf < 4; nf++) {
                    int col = col0 + wn * 64 + nf * 16 + llo;
                    C[(size_t)row * 1024 + col] = f2bf(acc[mf][nf][r] * scl);
                }
            }
        }
    }
}

__global__ __launch_bounds__(256)
void gemm_bf16(const u16* __restrict__ A, const u16* __restrict__ Bt,
               u16* __restrict__ C, int M, long sA, long sB, long sC,
               int scaleMask) {
    __shared__ __align__(16) u16 sa[128 * 64];
    __shared__ __align__(16) u16 sb[128 * 64];
    A  += (size_t)blockIdx.z * sA;
    Bt += (size_t)blockIdx.z * sB;
    C  += (size_t)blockIdx.z * sC;
    const float scl = ((scaleMask >> blockIdx.z) & 1) ? SCALE_Q : 1.0f;
    gemm128_body(A, Bt, C, M, scl, sa, sb, blockIdx.y * 128, blockIdx.x * 128);
}

// mem K/V (z=0,1; M=512) + persona K/V (z=2,3; M=64) in ONE dispatch
__global__ __launch_bounds__(256)
void gemm_small(u16* __restrict__ ws) {
    const int z = blockIdx.z;
    if (z >= 2 && blockIdx.y > 0) return;
    __shared__ __align__(16) u16 sa[128 * 64];
    __shared__ __align__(16) u16 sb[128 * 64];
    const u16* A = ws + ((z < 2) ? MEMBO : PERBO);
    const int M = (z < 2) ? 512 : 64;
    const u16* Bt = ws + WTO + (size_t)z * M1;     // wk2,wv2,wk3,wv3
    u16* C = ws + (z == 0 ? K2O : z == 1 ? V2O : z == 2 ? K3O : V3O);
    gemm128_body(A, Bt, C, M, 1.0f, sa, sb, blockIdx.y * 128, blockIdx.x * 128);
}

// ---------------------------------------------------------------------------
// Merged attention (r8-exact): swapped-operand MFMA, fixed-shift softmax,
// single-buffer staging, split-KV for long-causal qb>=8, 1152 blocks LPT.
// ---------------------------------------------------------------------------
__global__ __launch_bounds__(256)
void attn_tiled(u16* __restrict__ ws) {
    __shared__ __align__(16) u16 ksm[64 * 64];
    __shared__ __align__(16) u16 vtm[64 * 64];
    __shared__ __align__(16) u16 psm[4][16][72];

    const int blk = blockIdx.x;
    int branch, h, qb, pair = 0, half = 0;
    bool partial = false;
    if (blk < 256) {
        pair = blk >> 1; half = blk & 1;
        qb = 15 - (pair >> 4); h = pair & 15;       // qb 8..15
        branch = 1; partial = true;
    } else if (blk < 384) { int t = blk - 256; branch = 1; qb = 7 - (t >> 4);  h = t & 15; }
    else if (blk < 640)   { int t = blk - 384; branch = 0; qb = 15 - (t >> 4); h = t & 15; }
    else if (blk < 896)   { int t = blk - 640; branch = 2; qb = t >> 4;        h = t & 15; }
    else                  { int t = blk - 896; branch = 3; qb = t >> 4;        h = t & 15; }

    size_t kb_, vb_; int Skv, maskMode;
    if (branch == 0)      { kb_ = KVO;          vb_ = XBO;  Skv = 2048; maskMode = 2; }
    else if (branch == 1) { kb_ = KVO + 4 * M1; vb_ = VT1O; Skv = 2048; maskMode = 1; }
    else if (branch == 2) { kb_ = K2O;          vb_ = VT2O; Skv = 512;  maskMode = 0; }
    else                  { kb_ = K3O;          vb_ = VT3O; Skv = 64;   maskMode = 0; }
    const u16* Kp  = ws + kb_;
    const u16* VTp = ws + vb_;
    u16* Qp = ws + QO + (size_t)branch * 2 * M1;

    const int tid = threadIdx.x, wid = tid >> 6, lane = tid & 63;
    const int llo = lane & 15, lhi = lane >> 4;
    const int q0 = qb * 128;
    const int qw = q0 + wid * 32;          // this wave's 32 q rows
    const int hoff = h * 64;

    int tBeg, tEnd;
    if (partial) {
        int n = qb + 1;
        tBeg = half * n; tEnd = tBeg + n;
    } else {
        tEnd = maskMode ? (qb * 2 + 2) : (Skv >> 6);
        tBeg = (maskMode == 2 && q0 >= WIN) ? ((q0 - WIN) >> 6) : 0;
    }
    int myBeg = tBeg, myEnd = tEnd;
    if (maskMode) { int e = ((qw + 31) >> 6) + 1; if (e < myEnd) myEnd = e; }
    if (maskMode == 2 && qw >= WIN) { int b = (qw - WIN) >> 6; if (b > myBeg) myBeg = b; }

    bfrag qf[2][2];
#pragma unroll
    for (int sub = 0; sub < 2; sub++)
#pragma unroll
        for (int ds = 0; ds < 2; ds++)
            qf[sub][ds] = *reinterpret_cast<const bfrag*>(
                &Qp[(size_t)(qw + sub * 16 + llo) * 1024 + hoff + ds * 32 + lhi * 8]);

    facc ot[2][4];
    float lsum[2] = {0.f, 0.f};
#pragma unroll
    for (int sub = 0; sub < 2; sub++)
#pragma unroll
        for (int db = 0; db < 4; db++)
#pragma unroll
            for (int k = 0; k < 4; k++) ot[sub][db][k] = 0.f;

    const int srow = lane >> 3, schunk = lane & 7;

    for (int kt = tBeg; kt < tEnd; kt++) {
        __syncthreads();
#pragma unroll
        for (int j = 0; j < 2; j++) {
            int r = wid * 16 + j * 8 + srow;
            int ck = schunk ^ (r & 7);
            gload16(&Kp[(size_t)(kt * 64 + r) * 1024 + hoff + ck * 8],
                    &ksm[(wid * 2 + j) * 512]);
            gload16(&VTp[(size_t)(hoff + r) * Skv + kt * 64 + ck * 8],
                    &vtm[(wid * 2 + j) * 512]);
        }
        __syncthreads();

        if (kt >= myBeg && kt < myEnd) {
            bfrag kf[4][2], vf[4][2];
#pragma unroll
            for (int nf = 0; nf < 4; nf++)
#pragma unroll
                for (int ds = 0; ds < 2; ds++) {
                    int r = nf * 16 + llo;
                    int p = (ds * 4 + lhi) ^ (r & 7);
                    kf[nf][ds] = *reinterpret_cast<const bfrag*>(
                        &ksm[r * 64 + p * 8]);
                }
#pragma unroll
            for (int db = 0; db < 4; db++)
#pragma unroll
                for (int ks = 0; ks < 2; ks++) {
                    int d = db * 16 + llo;
                    int p = (ks * 4 + lhi) ^ (d & 7);
                    vf[db][ks] = *reinterpret_cast<const bfrag*>(
                        &vtm[d * 64 + p * 8]);
                }

#pragma unroll
            for (int sub = 0; sub < 2; sub++) {
                const int qsb = qw + sub * 16;
                facc st[4];
#pragma unroll
                for (int nf = 0; nf < 4; nf++)
#pragma unroll
                    for (int k = 0; k < 4; k++) st[nf][k] = 0.f;
                __builtin_amdgcn_s_setprio(1);
#pragma unroll
                for (int nf = 0; nf < 4; nf++)
#pragma unroll
                    for (int ds = 0; ds < 2; ds++)
                        st[nf] = __builtin_amdgcn_mfma_f32_16x16x32_bf16(
                            kf[nf][ds], qf[sub][ds], st[nf], 0, 0, 0);
                __builtin_amdgcn_s_setprio(0);

                float s[16];
#pragma unroll
                for (int nf = 0; nf < 4; nf++)
#pragma unroll
                    for (int r = 0; r < 4; r++) s[nf * 4 + r] = st[nf][r];

                const bool needC = maskMode && (kt * 64 + 63 > qsb);
                const bool needW = (maskMode == 2) && (kt * 64 < qsb + 15 - WIN);
                if (needC || needW) {
                    const int qi = qsb + llo;
#pragma unroll
                    for (int nf = 0; nf < 4; nf++)
#pragma unroll
                        for (int r = 0; r < 4; r++) {
                            int key = kt * 64 + nf * 16 + lhi * 4 + r;
                            if ((needC && key > qi) || (needW && (qi - key) > WIN))
                                s[nf * 4 + r] = -1e30f;
                        }
                }
                float p[16];
#pragma unroll
                for (int i = 0; i < 16; i++)
                    p[i] = __builtin_amdgcn_exp2f(s[i] - SM_SHIFT);
#pragma unroll
                for (int i = 0; i < 16; i++) lsum[sub] += p[i];

#pragma unroll
                for (int nf = 0; nf < 4; nf++)
#pragma unroll
                    for (int rp = 0; rp < 2; rp++) {
                        u32 w = cvt_pk(p[nf * 4 + rp * 2], p[nf * 4 + rp * 2 + 1]);
                        *reinterpret_cast<u32*>(
                            &psm[wid][llo][nf * 16 + lhi * 4 + rp * 2]) = w;
                    }
                bfrag pf0 = *reinterpret_cast<const bfrag*>(&psm[wid][llo][lhi * 8]);
                bfrag pf1 = *reinterpret_cast<const bfrag*>(&psm[wid][llo][32 + lhi * 8]);
                __builtin_amdgcn_s_setprio(1);
#pragma unroll
                for (int db = 0; db < 4; db++) {
                    ot[sub][db] = __builtin_amdgcn_mfma_f32_16x16x32_bf16(
                        vf[db][0], pf0, ot[sub][db], 0, 0, 0);
                    ot[sub][db] = __builtin_amdgcn_mfma_f32_16x16x32_bf16(
                        vf[db][1], pf1, ot[sub][db], 0, 0, 0);
                }
                __builtin_amdgcn_s_setprio(0);
            }
        }
    }

    if (!partial) {
#pragma unroll
        for (int sub = 0; sub < 2; sub++) {
            float l = lsum[sub];
            l += __shfl_xor(l, 16);
            l += __shfl_xor(l, 32);
            float inv = 1.f / l;
            u16* orow = &Qp[(size_t)(qw + sub * 16 + llo) * 1024 + hoff];
#pragma unroll
            for (int db = 0; db < 4; db++) {
                u16x4 pk;
#pragma unroll
                for (int r = 0; r < 4; r++) pk[r] = f2bf(ot[sub][db][r] * inv);
                *reinterpret_cast<u16x4*>(&orow[db * 16 + lhi * 4]) = pk;
            }
        }
    } else {
        float* rec = reinterpret_cast<float*>(ws) + (size_t)(pair * 2 + half) * RECSZ;
#pragma unroll
        for (int sub = 0; sub < 2; sub++) {
            float l = lsum[sub];
            l += __shfl_xor(l, 16);
            l += __shfl_xor(l, 32);
            rec[8192 + sub * 256 + tid] = l;
#pragma unroll
            for (int db = 0; db < 4; db++)
                *reinterpret_cast<facc*>(&rec[tid * 32 + sub * 16 + db * 4]) =
                    ot[sub][db];
        }
    }
}

// ---------------------------------------------------------------------------
// Combine split-KV halves: O = (O0 + O1) / (l0 + l1), write into Q1 region.
// ---------------------------------------------------------------------------
__global__ __launch_bounds__(256)
void combine_split(u16* __restrict__ ws) {
    const int pair = blockIdx.x;
    const int qb = 15 - (pair >> 4), h = pair & 15;
    const int tid = threadIdx.x, wid = tid >> 6, lane = tid & 63;
    const int llo = lane & 15, lhi = lane >> 4;
    const float* r0 = reinterpret_cast<const float*>(ws) + (size_t)(pair * 2) * RECSZ;
    const float* r1 = r0 + RECSZ;
    u16* Qp = ws + QO + 2 * M1;
    const int qw = qb * 128 + wid * 32;
#pragma unroll
    for (int sub = 0; sub < 2; sub++) {
        float inv = 1.f / (r0[8192 + sub * 256 + tid] + r1[8192 + sub * 256 + tid]);
        u16* orow = &Qp[(size_t)(qw + sub * 16 + llo) * 1024 + h * 64];
#pragma unroll
        for (int db = 0; db < 4; db++) {
            u16x4 pk;
#pragma unroll
            for (int r = 0; r < 4; r++) {
                float v = r0[tid * 32 + sub * 16 + db * 4 + r] +
                          r1[tid * 32 + sub * 16 + db * 4 + r];
                pk[r] = f2bf(v * inv);
            }
            *reinterpret_cast<u16x4*>(&orow[db * 16 + lhi * 4]) = pk;
        }
    }
}

// ---------------------------------------------------------------------------
// Gate + fuse (out4 bf16, stride 2M): g = softmax(concat @ gate_w + gate_b).
// ---------------------------------------------------------------------------
__global__ __launch_bounds__(256)
void gate_fuse(const u16* __restrict__ o4, const float* __restrict__ gw,
               const float* __restrict__ gb, float* __restrict__ out) {
    const int s = blockIdx.x, tid = threadIdx.x;
    const u16* ob0 = o4 + (size_t)s * H;
    float p[4] = {0.f, 0.f, 0.f, 0.f};
    for (int b = 0; b < 4; b++) {
        const u16* obb = ob0 + b * 2 * M1;
        const float* gwb = gw + (size_t)b * H * 4;
        for (int i = tid; i < H; i += 256) {
            float xv = bf2f(obb[i]);
            float4 g4 = *reinterpret_cast<const float4*>(&gwb[(size_t)i * 4]);
            p[0] += xv * g4.x; p[1] += xv * g4.y;
            p[2] += xv * g4.z; p[3] += xv * g4.w;
        }
    }
#pragma unroll
    for (int off = 1; off < 64; off <<= 1)
#pragma unroll
        for (int j = 0; j < 4; j++) p[j] += __shfl_xor(p[j], off);
    __shared__ float red[4][4];
    if ((tid & 63) == 0) {
        int w = tid >> 6;
#pragma unroll
        for (int j = 0; j < 4; j++) red[w][j] = p[j];
    }
    __syncthreads();
    float gl[4];
#pragma unroll
    for (int j = 0; j < 4; j++)
        gl[j] = gb[j] + red[0][j] + red[1][j] + red[2][j] + red[3][j];
    float mx = fmaxf(fmaxf(gl[0], gl[1]), fmaxf(gl[2], gl[3]));
    float e[4]; float tot = 0.f;
#pragma unroll
    for (int j = 0; j < 4; j++) { e[j] = __expf(gl[j] - mx); tot += e[j]; }
    float inv = 1.f / tot;
    int d = tid * 4;
    float4 rv; rv.x = rv.y = rv.z = rv.w = 0.f;
#pragma unroll
    for (int b = 0; b < 4; b++) {
        const u16* obb = ob0 + b * 2 * M1 + d;
        float wgt = e[b] * inv;
        rv.x += wgt * bf2f(obb[0]);
        rv.y += wgt * bf2f(obb[1]);
        rv.z += wgt * bf2f(obb[2]);
        rv.w += wgt * bf2f(obb[3]);
    }
    *reinterpret_cast<float4*>(&out[(size_t)s * H + d]) = rv;
}

// ---------------------------------------------------------------------------
// Orchestration.
// ---------------------------------------------------------------------------
extern "C" void kernel_launch(void* const* d_in, const int* in_sizes, int n_in,
                              void* d_out, int out_size, void* d_ws, size_t ws_size,
                              hipStream_t stream) {
    const float* Wm[16];
    for (int i = 0; i < 16; i++) Wm[i] = (const float*)d_in[i];
    const float* gw = (const float*)d_in[16];
    const float* gb = (const float*)d_in[17];
    const float* x = (const float*)d_in[18];
    const float* mem = (const float*)d_in[19];
    const float* per = (const float*)d_in[20];
    float* out = (float*)d_out;
    u16* ws = (u16*)d_ws;

    dim3 blk(256);
    cast_all<<<dim3(1312), blk, 0, stream>>>(x, mem, per, ws);

    // Phase A: all 8 weights in one transpose; 8-phase GEMM -> Q0..3,K0,V0,K1,V1
    transp_cast8<<<dim3(16, 16, 8), blk, 0, stream>>>(
        Wm[0], Wm[4], Wm[8], Wm[12], Wm[1], Wm[2], Wm[5], Wm[6], ws + WTO);
    gemm256<<<dim3(4, 8, 8), dim3(512), 0, stream>>>(
        ws + XBO, ws + WTO, ws + QO, (long)M1, (long)(2 * M1), 0xF);

    // Phase B: mem/persona K,V (one transpose + ONE merged small-GEMM dispatch)
    transp_cast8<<<dim3(16, 16, 4), blk, 0, stream>>>(
        Wm[9], Wm[10], Wm[13], Wm[14], Wm[9], Wm[10], Wm[13], Wm[14], ws + WTO);
    gemm_small<<<dim3(8, 4, 4), blk, 0, stream>>>(ws);

    // Phase C: V transposes (VT0 overlays XB), merged attention, split-combine
    transp_v<<<dim3(32, 16, 4), blk, 0, stream>>>(ws);
    attn_tiled<<<dim3(1152), blk, 0, stream>>>(ws);
    combine_split<<<dim3(128), blk, 0, stream>>>(ws);

    // Phase D: O-projection
    transp_cast8<<<dim3(16, 16, 4), blk, 0, stream>>>(
        Wm[3], Wm[7], Wm[11], Wm[15], Wm[3], Wm[7], Wm[11], Wm[15], ws + WTO);
    gemm_bf16<<<dim3(8, 16, 4), blk, 0, stream>>>(
        ws + QO, ws + WTO, ws + KVO, 2048, (long)(2 * M1), (long)M1,
        (long)(2 * M1), 0);

    // Phase E
    gate_fuse<<<dim3(S), blk, 0, stream>>>(ws + KVO, gw, gb, out);
}